// Round 2
// baseline (2852.440 us; speedup 1.0000x reference)
//
#include <hip/hip_runtime.h>
#include <hip/hip_bf16.h>

typedef __hip_bfloat16 bf16;

#define B_WIN 2048
#define NTOK 66
#define DIMC 256
#define NH 8
#define HD 32

// ---------------------------------------------------------------------------
// Kernel 1: fused QKV projection + windowed attention for one (batch, head).
// Grid: B_WIN*NH blocks of 256 threads. All inputs fp32.
//   phase A: qkv = x @ Wqkv^T + b  (head's 96 rows), register-blocked
//   phase B: S = scale*Q@K^T + rel_bias ; softmax rows
//   phase C: y = P@V   -> ws laid out [B][N][H*HD] (proj-ready)
// YT = storage type of the y intermediate (float if ws fits, else bf16).
// ---------------------------------------------------------------------------
template <typename YT>
__global__ __launch_bounds__(256) void attn_kernel(
    const float* __restrict__ x,      // [B,66,256]
    const float* __restrict__ qkv_w,  // [768,256]
    const float* __restrict__ qkv_b,  // [768]
    const float* __restrict__ btab,   // [225,8]
    const int*  __restrict__ tnp,     // scalar token_num (=2)
    YT* __restrict__ y)               // [B,66,256] attention output
{
    // union-style LDS: phase A uses xc[66][65] + wc[96][65] (10530 f),
    // phase B/C uses qs/ks/vs[66][33] + sc[66][67] (10956 f)
    __shared__ float smem[10956];
    float* xc = smem;            // [66][65]
    float* wc = smem + 4290;     // [96][65]
    float* qs = smem;            // [66][33]
    float* ks = smem + 2178;     // [66][33]
    float* vs = smem + 4356;     // [66][33]
    float* sc = smem + 6534;     // [66][67]

    const int b   = blockIdx.x >> 3;
    const int h   = blockIdx.x & 7;
    const int tid = threadIdx.x;
    const int d   = tid & 31;    // head dim this thread owns
    const int g   = tid >> 5;    // n-group 0..7
    const int tn  = *tnp;

    const size_t xbase = (size_t)b * (NTOK * DIMC);

    // ---- phase A: per-thread accumulators for q/k/v over 9 n-positions ----
    float aq[9], ak[9], av[9];
    {
        float bq = qkv_b[h*HD + d];
        float bk = qkv_b[256 + h*HD + d];
        float bv = qkv_b[512 + h*HD + d];
        #pragma unroll
        for (int i = 0; i < 9; ++i) { aq[i] = bq; ak[i] = bk; av[i] = bv; }
    }

    for (int cc = 0; cc < DIMC; cc += 64) {
        // stage x chunk [66][64] (+1 pad)
        for (int idx = tid; idx < NTOK*64; idx += 256) {
            int n = idx >> 6, c = idx & 63;
            xc[n*65 + c] = x[xbase + n*DIMC + cc + c];
        }
        // stage this head's 96 weight rows, chunk [96][64] (+1 pad)
        for (int idx = tid; idx < 96*64; idx += 256) {
            int r = idx >> 6, c = idx & 63;
            int grow = (r >> 5) * 256 + h*HD + (r & 31);   // q/k/v row in [768]
            wc[r*65 + c] = qkv_w[(size_t)grow*DIMC + cc + c];
        }
        __syncthreads();
        for (int c = 0; c < 64; ++c) {
            float wq = wc[d*65 + c];
            float wk = wc[(32+d)*65 + c];
            float wv = wc[(64+d)*65 + c];
            #pragma unroll
            for (int i = 0; i < 9; ++i) {
                int n = g + (i << 3);
                if (n < NTOK) {
                    float xx = xc[n*65 + c];
                    aq[i] = fmaf(xx, wq, aq[i]);
                    ak[i] = fmaf(xx, wk, ak[i]);
                    av[i] = fmaf(xx, wv, av[i]);
                }
            }
        }
        __syncthreads();   // also protects the aliasing write below after last chunk
    }

    // write q/k/v fragments to LDS (aliases xc/wc — safe after barrier)
    #pragma unroll
    for (int i = 0; i < 9; ++i) {
        int n = g + (i << 3);
        if (n < NTOK) {
            qs[n*33 + d] = aq[i];
            ks[n*33 + d] = ak[i];
            vs[n*33 + d] = av[i];
        }
    }
    __syncthreads();

    // ---- phase B: scores + relative-position bias ----
    const float scale = 0.17677669529663687f;   // 32^-0.5
    for (int o = tid; o < NTOK*NTOK; o += 256) {
        int i = o / 66;
        int j = o - i*66;
        float acc = 0.f;
        #pragma unroll
        for (int c = 0; c < HD; ++c) acc = fmaf(qs[i*33 + c], ks[j*33 + c], acc);
        acc *= scale;
        if (i >= tn && j >= tn) {
            int ri = i - tn, rj = j - tn;
            int bidx = ((ri >> 3) - (rj >> 3) + 7) * 15 + ((ri & 7) - (rj & 7) + 7);
            acc += btab[bidx*NH + h];
        }
        sc[i*67 + j] = acc;
    }
    __syncthreads();

    // ---- softmax over rows (66 rows, thread per row) ----
    if (tid < NTOK) {
        float mx = -1e30f;
        for (int j = 0; j < NTOK; ++j) mx = fmaxf(mx, sc[tid*67 + j]);
        float sum = 0.f;
        for (int j = 0; j < NTOK; ++j) {
            float e = __expf(sc[tid*67 + j] - mx);
            sc[tid*67 + j] = e;
            sum += e;
        }
        float inv = 1.f / sum;
        for (int j = 0; j < NTOK; ++j) sc[tid*67 + j] *= inv;
    }
    __syncthreads();

    // ---- phase C: out = P @ V, write [B][n][h*32+d] ----
    for (int o = tid; o < NTOK*HD; o += 256) {
        int i = o >> 5, dd = o & 31;
        float acc = 0.f;
        for (int j = 0; j < NTOK; ++j)
            acc = fmaf(sc[i*67 + j], vs[j*33 + dd], acc);
        y[xbase + i*DIMC + h*HD + dd] = (YT)acc;
    }
}

// ---------------------------------------------------------------------------
// Kernel 2: output projection  out = y @ proj_w^T + proj_b
// Grid: B_WIN blocks of 256 threads; thread t owns output column t.
// y staged transposed [c][n] so 4 n's load as one float4 broadcast.
// ---------------------------------------------------------------------------
template <typename YT>
__global__ __launch_bounds__(256) void proj_kernel(
    const YT* __restrict__ y,       // [B,66,256]
    const float* __restrict__ pw,   // [256,256]
    const float* __restrict__ pb,   // [256]
    float* __restrict__ out)        // [B,66,256]
{
    __shared__ float yT[32][68];    // [c][n], n padded 66->68 (zeros)
    __shared__ float wcs[256][33];  // [row][c], +1 pad -> bank (t+c)%32
    const int b = blockIdx.x;
    const int t = threadIdx.x;
    const size_t base = (size_t)b * (NTOK * DIMC);

    float acc[68];
    #pragma unroll
    for (int n = 0; n < 68; ++n) acc[n] = 0.f;

    for (int cc = 0; cc < DIMC; cc += 32) {
        for (int idx = t; idx < NTOK*32; idx += 256) {
            int n = idx >> 5, c = idx & 31;
            yT[c][n] = (float)y[base + n*DIMC + cc + c];
        }
        if (t < 64) yT[t >> 1][66 + (t & 1)] = 0.f;   // zero the pad columns
        for (int idx = t; idx < 256*32; idx += 256) {
            int r = idx >> 5, c = idx & 31;
            wcs[r][c] = pw[(size_t)r*DIMC + cc + c];
        }
        __syncthreads();
        for (int c = 0; c < 32; ++c) {
            float w = wcs[t][c];
            #pragma unroll
            for (int ng = 0; ng < 17; ++ng) {
                const float4 y4 = *(const float4*)&yT[c][ng*4];
                acc[ng*4+0] = fmaf(y4.x, w, acc[ng*4+0]);
                acc[ng*4+1] = fmaf(y4.y, w, acc[ng*4+1]);
                acc[ng*4+2] = fmaf(y4.z, w, acc[ng*4+2]);
                acc[ng*4+3] = fmaf(y4.w, w, acc[ng*4+3]);
            }
        }
        __syncthreads();
    }

    float pbv = pb[t];
    for (int n = 0; n < NTOK; ++n)
        out[base + n*DIMC + t] = acc[n] + pbv;
}

extern "C" void kernel_launch(void* const* d_in, const int* in_sizes, int n_in,
                              void* d_out, int out_size, void* d_ws, size_t ws_size,
                              hipStream_t stream) {
    const float* x      = (const float*)d_in[0];
    const float* qkv_w  = (const float*)d_in[1];
    const float* qkv_b  = (const float*)d_in[2];
    const float* btab   = (const float*)d_in[3];
    const float* pw     = (const float*)d_in[4];
    const float* pb     = (const float*)d_in[5];
    const int*   tnp    = (const int*)d_in[6];
    float* out = (float*)d_out;

    const size_t yelems = (size_t)B_WIN * NTOK * DIMC;
    if (ws_size >= yelems * sizeof(float)) {
        float* yws = (float*)d_ws;    // 138 MB fp32 intermediate
        attn_kernel<float><<<B_WIN * NH, 256, 0, stream>>>(x, qkv_w, qkv_b, btab, tnp, yws);
        proj_kernel<float><<<B_WIN, 256, 0, stream>>>(yws, pw, pb, out);
    } else {
        bf16* yws = (bf16*)d_ws;      // 69 MB bf16 fallback
        attn_kernel<bf16><<<B_WIN * NH, 256, 0, stream>>>(x, qkv_w, qkv_b, btab, tnp, yws);
        proj_kernel<bf16><<<B_WIN, 256, 0, stream>>>(yws, pw, pb, out);
    }
}

// Round 3
// 1517.852 us; speedup vs baseline: 1.8793x; 1.8793x over previous
//
#include <hip/hip_runtime.h>
#include <hip/hip_bf16.h>

typedef __attribute__((ext_vector_type(8))) short short8;
typedef __attribute__((ext_vector_type(4))) float float4v;

#define B_WIN 2048
#define NT 66
#define DIMC 256
#define NH 8
#define HD 32

// ws layout (bytes)
#define WS_WQKV 0          // [768][256] bf16 = 393216
#define WS_PW   393216     // [256][256] bf16 = 131072
#define WS_BMAT 524288     // [8][80][80] fp32 = 204800  (total 729088)

// LDS pool layout (bytes), phase-unioned
#define OFF_XB   0         // phase A: x bf16 [66][264]  (stride 528 B)
#define OFF_WBUF 34848     // phase A: W chunk [96(+pad 128)][40] (stride 80 B)
#define OFF_QH   45088     // Q bf16 [66][40] (scale+bias folded)
#define OFF_KH   50368     // K bf16 [66][40]
#define OFF_VT   55648     // V^T bf16 [32][104] (stride 208 B), cols 66..103 zero
#define POOL_SZ  62304
// overlays (after phase A):
#define OFF_P    0         // P=exp(S) bf16 [80][104] (stride 208 B)
#define OFF_YH   34848     // y_head bf16 [66][40]
#define OFF_PWH  0         // phase D: proj_w head-slice bf16 [256][40]

static __device__ __forceinline__ unsigned short f2b(float f) {
    __hip_bfloat16 h = __float2bfloat16(f);
    return *reinterpret_cast<unsigned short*>(&h);
}

// ---------------------------------------------------------------------------
// prep: fp32->bf16 weight conversion + bias matrix with masking folded in
// ---------------------------------------------------------------------------
__global__ __launch_bounds__(256) void prep_kernel(
    const float* __restrict__ qkv_w, const float* __restrict__ pw,
    const float* __restrict__ btab, const int* __restrict__ tnp,
    unsigned short* __restrict__ wqkv_bf, unsigned short* __restrict__ pwbf,
    float* __restrict__ Bmat)
{
    int gid = blockIdx.x * 256 + threadIdx.x;
    if (gid < 768 * 256) wqkv_bf[gid] = f2b(qkv_w[gid]);
    if (gid < 256 * 256) pwbf[gid] = f2b(pw[gid]);
    if (gid < 8 * 80 * 80) {
        int h = gid / 6400, rem = gid % 6400, i = rem / 80, j = rem % 80;
        int tn = *tnp;
        float v;
        if (j >= NT) v = -1e30f;                          // mask j-padding (P=0)
        else if (i >= NT || i < tn || j < tn) v = 0.f;    // token rows/cols: no bias
        else {
            int ri = i - tn, rj = j - tn;
            int bidx = (((ri >> 3) - (rj >> 3) + 7) * 15) + ((ri & 7) - (rj & 7) + 7);
            v = btab[bidx * NH + h];
        }
        Bmat[gid] = v;
    }
}

// ---------------------------------------------------------------------------
// out init: out[b][n][c] = proj_b[c]  (atomic partials land on top)
// ---------------------------------------------------------------------------
__global__ __launch_bounds__(256) void outinit_kernel(
    const float* __restrict__ pb, float* __restrict__ out)
{
    long long i4 = (long long)(blockIdx.x * 256 + threadIdx.x) * 4;
    if (i4 < (long long)B_WIN * NT * DIMC) {
        float4 v = *(const float4*)(pb + ((int)i4 & 255));
        *(float4*)(out + i4) = v;
    }
}

// ---------------------------------------------------------------------------
// fused per-(b,h): QKV GEMM -> QK^T(+bias,+exp) -> PV(/rowsum) -> proj partial
// grid 16384: b = blk & 2047, h = blk >> 11 (keeps all heads of b on one XCD)
// ---------------------------------------------------------------------------
__global__ __launch_bounds__(256, 2) void attn_fused_kernel(
    const float* __restrict__ x,
    const unsigned short* __restrict__ wqkv_bf,
    const unsigned short* __restrict__ pwbf,
    const float* __restrict__ qkv_b,
    const float* __restrict__ Bmat,
    float* __restrict__ out)
{
    __shared__ __align__(16) char pool[POOL_SZ];
    __shared__ float rowsum[80];

    const int tid = threadIdx.x;
    const int l = tid & 63, w = tid >> 6;      // lane, wave
    const int q = l >> 4, cl = l & 15;         // quad, low-lane
    const int b = blockIdx.x & 2047, h = blockIdx.x >> 11;
    const size_t xbase = (size_t)b * (NT * DIMC);

    // ---- setup: zero V^T, stage x -> bf16 LDS ----
    for (int i = tid; i < 32 * 104 / 2; i += 256)
        ((unsigned int*)(pool + OFF_VT))[i] = 0u;
    for (int i = tid; i < NT * 64; i += 256) {
        int m = i >> 6, c4 = (i & 63) << 2;
        float4 xv = *(const float4*)(x + xbase + m * DIMC + c4);
        unsigned short h4[4] = { f2b(xv.x), f2b(xv.y), f2b(xv.z), f2b(xv.w) };
        *(ulonglong1*)(pool + OFF_XB + m * 528 + c4 * 2) = *(ulonglong1*)h4;
    }
    __syncthreads();

    // ---- phase A: QKV = x @ Wqkv(96 rows for head h)^T, tiles 5m x 6n ----
    const int ntiles = (w < 2) ? 8 : 7;        // tiles t = w + 4i over 30
    float4v acc[8];
    #pragma unroll
    for (int i = 0; i < 8; ++i) acc[i] = (float4v){0.f, 0.f, 0.f, 0.f};

    for (int kc = 0; kc < 8; ++kc) {           // K chunks of 32
        for (int i = tid; i < 768; i += 256) { // stage 96x32 bf16 (ushort4)
            int r = i >> 3, c4 = (i & 7) << 2;
            int grow = ((r >> 5) << 8) + (h << 5) + (r & 31);
            *(ulonglong1*)(pool + OFF_WBUF + r * 80 + c4 * 2) =
                *(const ulonglong1*)(wqkv_bf + grow * DIMC + (kc << 5) + c4);
        }
        __syncthreads();
        for (int i = 0; i < ntiles; ++i) {
            int t = w + 4 * i, mt = t % 5, nt = t / 5;
            int am = min(mt * 16 + cl, NT - 1);
            short8 a = *(const short8*)(pool + OFF_XB + am * 528 + (kc << 6) + (q << 4));
            short8 bb = *(const short8*)(pool + OFF_WBUF + (nt * 16 + cl) * 80 + (q << 4));
            acc[i] = __builtin_amdgcn_mfma_f32_16x16x32_bf16(a, bb, acc[i], 0, 0, 0);
        }
        __syncthreads();
    }

    // write Q (scaled), K, V^T to LDS
    for (int i = 0; i < ntiles; ++i) {
        int t = w + 4 * i, mt = t % 5, nt = t / 5;
        int ng = nt * 16 + cl;                  // 0..95
        int src = ng >> 5, cn = ng & 31;
        float bias = qkv_b[(src << 8) + (h << 5) + cn];
        #pragma unroll
        for (int r = 0; r < 4; ++r) {
            int m = mt * 16 + (q << 2) + r;
            if (m < NT) {
                float v = acc[i][r] + bias;
                if (src == 0)
                    *(unsigned short*)(pool + OFF_QH + m * 80 + cn * 2) =
                        f2b(v * 0.17677669529663687f);
                else if (src == 1)
                    *(unsigned short*)(pool + OFF_KH + m * 80 + cn * 2) = f2b(v);
                else
                    *(unsigned short*)(pool + OFF_VT + cn * 208 + m * 2) = f2b(v);
            }
        }
    }
    __syncthreads();   // QKV visible; xb dead -> P overlay OK

    // zero rowsum + P pad cols 80..95
    for (int i = tid; i < 80; i += 256) rowsum[i] = 0.f;
    for (int i = tid; i < 320; i += 256) {
        int m = i >> 2, c4 = 80 + ((i & 3) << 2);
        unsigned short z4[4] = {0, 0, 0, 0};
        *(ulonglong1*)(pool + OFF_P + m * 208 + c4 * 2) = *(ulonglong1*)z4;
    }
    __syncthreads();

    // ---- phase B: P = exp(Q@K^T + Bmat), rowsum accumulated ----
    for (int t = w; t < 25; t += 4) {
        int mt = t / 5, jt = t % 5;
        int am = min(mt * 16 + cl, NT - 1);
        int bj = min(jt * 16 + cl, NT - 1);
        short8 a = *(const short8*)(pool + OFF_QH + am * 80 + (q << 4));
        short8 bb = *(const short8*)(pool + OFF_KH + bj * 80 + (q << 4));
        float4v s = __builtin_amdgcn_mfma_f32_16x16x32_bf16(
            a, bb, (float4v){0.f, 0.f, 0.f, 0.f}, 0, 0, 0);
        int col = jt * 16 + cl;
        float rs[4];
        #pragma unroll
        for (int r = 0; r < 4; ++r) {
            int row = mt * 16 + (q << 2) + r;
            float p = __expf(s[r] + Bmat[(h * 80 + row) * 80 + col]);
            *(unsigned short*)(pool + OFF_P + row * 208 + col * 2) = f2b(p);
            rs[r] = p;
        }
        #pragma unroll
        for (int off = 1; off < 16; off <<= 1) {
            #pragma unroll
            for (int r = 0; r < 4; ++r) rs[r] += __shfl_xor(rs[r], off, 64);
        }
        if (cl == 0) {
            #pragma unroll
            for (int r = 0; r < 4; ++r)
                atomicAdd(&rowsum[mt * 16 + (q << 2) + r], rs[r]);
        }
    }
    __syncthreads();

    // ---- phase C: y = (P @ V) / rowsum ----
    const int npv = (w < 2) ? 3 : 2;           // tiles t = w + 4i over 10 (5m x 2n)
    float4v yacc[3];
    for (int i = 0; i < npv; ++i) {
        int t = w + 4 * i, mt = t % 5, nt = t / 5;
        float4v a4 = (float4v){0.f, 0.f, 0.f, 0.f};
        #pragma unroll
        for (int ks = 0; ks < 3; ++ks) {
            short8 a = *(const short8*)(pool + OFF_P + (mt * 16 + cl) * 208 + (ks << 6) + (q << 4));
            short8 bb = *(const short8*)(pool + OFF_VT + (nt * 16 + cl) * 208 + (ks << 6) + (q << 4));
            a4 = __builtin_amdgcn_mfma_f32_16x16x32_bf16(a, bb, a4, 0, 0, 0);
        }
        yacc[i] = a4;
    }
    for (int i = 0; i < npv; ++i) {
        int t = w + 4 * i, mt = t % 5, nt = t / 5;
        #pragma unroll
        for (int r = 0; r < 4; ++r) {
            int m = mt * 16 + (q << 2) + r;
            if (m < NT) {
                float inv = 1.f / rowsum[m];
                *(unsigned short*)(pool + OFF_YH + m * 80 + (nt * 16 + cl) * 2) =
                    f2b(yacc[i][r] * inv);
            }
        }
    }
    __syncthreads();   // yh visible; P/rowsum dead -> pwh overlay OK

    // ---- phase D: out[b] += y_h @ proj_w[:, 32h:32h+32]^T ----
    for (int i = tid; i < 2048; i += 256) {    // stage pwh [256][32]
        int r = i >> 3, c4 = (i & 7) << 2;
        *(ulonglong1*)(pool + OFF_PWH + r * 80 + c4 * 2) =
            *(const ulonglong1*)(pwbf + r * DIMC + (h << 5) + c4);
    }
    __syncthreads();
    for (int mt = 0; mt < 5; ++mt) {
        int am = min(mt * 16 + cl, NT - 1);
        short8 a = *(const short8*)(pool + OFF_YH + am * 80 + (q << 4));
        for (int j = 0; j < 4; ++j) {
            int nt = (w << 2) + j;
            short8 bb = *(const short8*)(pool + OFF_PWH + (nt * 16 + cl) * 80 + (q << 4));
            float4v o = __builtin_amdgcn_mfma_f32_16x16x32_bf16(
                a, bb, (float4v){0.f, 0.f, 0.f, 0.f}, 0, 0, 0);
            int col = nt * 16 + cl;
            #pragma unroll
            for (int r = 0; r < 4; ++r) {
                int m = mt * 16 + (q << 2) + r;
                if (m < NT)
                    atomicAdd(out + xbase + m * DIMC + col, o[r]);
            }
        }
    }
}

extern "C" void kernel_launch(void* const* d_in, const int* in_sizes, int n_in,
                              void* d_out, int out_size, void* d_ws, size_t ws_size,
                              hipStream_t stream) {
    const float* x     = (const float*)d_in[0];
    const float* qkv_w = (const float*)d_in[1];
    const float* qkv_b = (const float*)d_in[2];
    const float* btab  = (const float*)d_in[3];
    const float* pw    = (const float*)d_in[4];
    const float* pb    = (const float*)d_in[5];
    const int*   tnp   = (const int*)d_in[6];
    float* out = (float*)d_out;

    unsigned short* wqkv_bf = (unsigned short*)((char*)d_ws + WS_WQKV);
    unsigned short* pwbf    = (unsigned short*)((char*)d_ws + WS_PW);
    float*          Bmat    = (float*)((char*)d_ws + WS_BMAT);

    prep_kernel<<<768, 256, 0, stream>>>(qkv_w, pw, btab, tnp, wqkv_bf, pwbf, Bmat);
    outinit_kernel<<<(B_WIN * NT * DIMC / 4 + 255) / 256, 256, 0, stream>>>(pb, out);
    attn_fused_kernel<<<B_WIN * NH, 256, 0, stream>>>(x, wqkv_bf, pwbf, qkv_b, Bmat, out);
}